// Round 1
// baseline (59.191 us; speedup 1.0000x reference)
//
#include <hip/hip_runtime.h>

// EmbeddingBag group: 3 tables [NUM_EMB, 3] fp32, shared indices, B bags.
// out = concat([tile(p0,5), tile(p1,10), tile(p2,6)], axis=0)  -> [21B, 3]
//
// Kernel A: one wave (64 lanes) per bag. Lane l gathers row idx[start+l] from
// each of the 3 tables, shfl-tree reduces 9 floats, lane 0 writes the bag's
// sums into the FIRST replica slot of each tile region:
//   p0 -> row b, p1 -> row 5B+b, p2 -> row 15B+b.
// Kernel B: replicates the remaining 18B rows from those source regions.

__device__ __forceinline__ float wave_reduce_sum(float v) {
#pragma unroll
    for (int off = 32; off > 0; off >>= 1)
        v += __shfl_down(v, off, 64);
    return v;  // valid in lane 0
}

__global__ __launch_bounds__(256) void bag_sum_kernel(
    const int* __restrict__ eb_input,
    const int* __restrict__ eb_offset,
    const float* __restrict__ t0,
    const float* __restrict__ t1,
    const float* __restrict__ t2,
    float* __restrict__ out,
    int N, int B)
{
    const int wave = (blockIdx.x * blockDim.x + threadIdx.x) >> 6;
    const int lane = threadIdx.x & 63;
    if (wave >= B) return;

    const int start = eb_offset[wave];
    const int end   = (wave + 1 < B) ? eb_offset[wave + 1] : N;

    float s0x = 0.f, s0y = 0.f, s0z = 0.f;
    float s1x = 0.f, s1y = 0.f, s1z = 0.f;
    float s2x = 0.f, s2y = 0.f, s2z = 0.f;

    for (int i = start + lane; i < end; i += 64) {
        const long long j = (long long)eb_input[i] * 3;
        const float* __restrict__ p0 = t0 + j;
        const float* __restrict__ p1 = t1 + j;
        const float* __restrict__ p2 = t2 + j;
        s0x += p0[0]; s0y += p0[1]; s0z += p0[2];
        s1x += p1[0]; s1y += p1[1]; s1z += p1[2];
        s2x += p2[0]; s2y += p2[1]; s2z += p2[2];
    }

    s0x = wave_reduce_sum(s0x); s0y = wave_reduce_sum(s0y); s0z = wave_reduce_sum(s0z);
    s1x = wave_reduce_sum(s1x); s1y = wave_reduce_sum(s1y); s1z = wave_reduce_sum(s1z);
    s2x = wave_reduce_sum(s2x); s2y = wave_reduce_sum(s2y); s2z = wave_reduce_sum(s2z);

    if (lane == 0) {
        const size_t b = (size_t)wave;
        float* o0 = out + b * 3;                        // p0, replica 0 (rows [0, B))
        float* o1 = out + ((size_t)5  * B + b) * 3;     // p1, replica 0 (rows [5B, 6B))
        float* o2 = out + ((size_t)15 * B + b) * 3;     // p2, replica 0 (rows [15B, 16B))
        o0[0] = s0x; o0[1] = s0y; o0[2] = s0z;
        o1[0] = s1x; o1[1] = s1y; o1[2] = s1z;
        o2[0] = s2x; o2[1] = s2y; o2[2] = s2z;
    }
}

__global__ __launch_bounds__(256) void tile_kernel(float* __restrict__ out, int B)
{
    const int r = blockIdx.x * blockDim.x + threadIdx.x;
    const int total = 18 * B;  // rows still to fill
    if (r >= total) return;

    size_t dst, src;
    if (r < 4 * B) {                 // p0 replicas 1..4 -> rows [B, 5B)
        dst = (size_t)B + r;
        src = (size_t)(r % B);
    } else if (r < 13 * B) {         // p1 replicas 1..9 -> rows [6B, 15B)
        const int q = r - 4 * B;
        dst = (size_t)6 * B + q;
        src = (size_t)5 * B + (q % B);
    } else {                         // p2 replicas 1..5 -> rows [16B, 21B)
        const int q = r - 13 * B;
        dst = (size_t)16 * B + q;
        src = (size_t)15 * B + (q % B);
    }

    const float* __restrict__ s = out + src * 3;
    float* __restrict__ d = out + dst * 3;
    const float a = s[0], b = s[1], c = s[2];
    d[0] = a; d[1] = b; d[2] = c;
}

extern "C" void kernel_launch(void* const* d_in, const int* in_sizes, int n_in,
                              void* d_out, int out_size, void* d_ws, size_t ws_size,
                              hipStream_t stream)
{
    const int*   eb_input  = (const int*)d_in[0];
    const int*   eb_offset = (const int*)d_in[1];
    const float* t0        = (const float*)d_in[2];
    const float* t1        = (const float*)d_in[3];
    const float* t2        = (const float*)d_in[4];
    float*       out       = (float*)d_out;

    const int N = in_sizes[0];   // 819200
    const int B = in_sizes[1];   // 16384

    // Kernel A: one wave per bag; 4 waves (256 threads) per block.
    const int blocksA = (B + 3) / 4;
    bag_sum_kernel<<<blocksA, 256, 0, stream>>>(eb_input, eb_offset, t0, t1, t2, out, N, B);

    // Kernel B: one thread per remaining output row (18B rows).
    const int totalRows = 18 * B;
    const int blocksB = (totalRows + 255) / 256;
    tile_kernel<<<blocksB, 256, 0, stream>>>(out, B);
}

// Round 2
// 57.386 us; speedup vs baseline: 1.0315x; 1.0315x over previous
//
#include <hip/hip_runtime.h>

// EmbeddingBag group, fused: 3 tables [10M, 3] fp32, shared indices, B bags.
// out = concat([tile(p0,5), tile(p1,10), tile(p2,6)], axis=0) -> [21B, 3]
//
// Single kernel: each wave handles TWO bags (32 lanes per bag, 2 indices per
// lane -> 6 independent row-gathers in flight per lane). Butterfly shfl_xor
// reduce within each 32-lane half leaves all 9 sums in every lane; lanes 0..20
// of each half then write all 21 replica rows for their bag directly.

__global__ __launch_bounds__(256) void bag_fused_kernel(
    const int* __restrict__ eb_input,
    const int* __restrict__ eb_offset,
    const float* __restrict__ t0,
    const float* __restrict__ t1,
    const float* __restrict__ t2,
    float* __restrict__ out,
    int N, int B)
{
    const int wid  = (blockIdx.x * blockDim.x + threadIdx.x) >> 6;
    const int lane = threadIdx.x & 63;
    const int l5   = lane & 31;           // lane within half
    const int b    = wid * 2 + (lane >> 5);  // bag id (one per 32-lane half)
    if (b >= B) return;

    const int start = eb_offset[b];
    const int end   = (b + 1 < B) ? eb_offset[b + 1] : N;

    float s0x = 0.f, s0y = 0.f, s0z = 0.f;
    float s1x = 0.f, s1y = 0.f, s1z = 0.f;
    float s2x = 0.f, s2y = 0.f, s2z = 0.f;

    for (int i = start + l5; i < end; i += 32) {
        const unsigned idx = (unsigned)eb_input[i];
        const size_t byteoff = (size_t)(idx * 12u);   // < 120 MB, fits u32
        const float* __restrict__ p0 = (const float*)((const char*)t0 + byteoff);
        const float* __restrict__ p1 = (const float*)((const char*)t1 + byteoff);
        const float* __restrict__ p2 = (const float*)((const char*)t2 + byteoff);
        s0x += p0[0]; s0y += p0[1]; s0z += p0[2];
        s1x += p1[0]; s1y += p1[1]; s1z += p1[2];
        s2x += p2[0]; s2y += p2[1]; s2z += p2[2];
    }

    // Butterfly reduce within each 32-lane half (offsets 16..1 never cross
    // the half boundary). Every lane ends with the full 9 sums for its bag.
#pragma unroll
    for (int off = 16; off > 0; off >>= 1) {
        s0x += __shfl_xor(s0x, off, 64);
        s0y += __shfl_xor(s0y, off, 64);
        s0z += __shfl_xor(s0z, off, 64);
        s1x += __shfl_xor(s1x, off, 64);
        s1y += __shfl_xor(s1y, off, 64);
        s1z += __shfl_xor(s1z, off, 64);
        s2x += __shfl_xor(s2x, off, 64);
        s2y += __shfl_xor(s2y, off, 64);
        s2z += __shfl_xor(s2z, off, 64);
    }

    // Lanes 0..20 of each half write the 21 replica rows for bag b:
    //   rows [0,5B):  tile(p0,5)   -> row l5*B + b, l5 in [0,5)
    //   rows [5B,15B): tile(p1,10) -> row l5*B + b, l5 in [5,15)
    //   rows [15B,21B): tile(p2,6) -> row l5*B + b, l5 in [15,21)
    if (l5 < 21) {
        float x, y, z;
        if (l5 < 5)       { x = s0x; y = s0y; z = s0z; }
        else if (l5 < 15) { x = s1x; y = s1y; z = s1z; }
        else              { x = s2x; y = s2y; z = s2z; }
        float* __restrict__ d = out + ((size_t)l5 * B + b) * 3;
        d[0] = x; d[1] = y; d[2] = z;
    }
}

extern "C" void kernel_launch(void* const* d_in, const int* in_sizes, int n_in,
                              void* d_out, int out_size, void* d_ws, size_t ws_size,
                              hipStream_t stream)
{
    const int*   eb_input  = (const int*)d_in[0];
    const int*   eb_offset = (const int*)d_in[1];
    const float* t0        = (const float*)d_in[2];
    const float* t1        = (const float*)d_in[3];
    const float* t2        = (const float*)d_in[4];
    float*       out       = (float*)d_out;

    const int N = in_sizes[0];   // 819200
    const int B = in_sizes[1];   // 16384

    // 2 bags per wave, 4 waves per block -> 8 bags per block.
    const int waves  = (B + 1) / 2;
    const int blocks = (waves + 3) / 4;
    bag_fused_kernel<<<blocks, 256, 0, stream>>>(eb_input, eb_offset, t0, t1, t2, out, N, B);
}